// Round 7
// baseline (258.751 us; speedup 1.0000x reference)
//
#include <hip/hip_runtime.h>
#include <stdint.h>

constexpr int kHW = 16384;   // 128*128 pixels (grid shared across batch)
constexpr int kB  = 4;
constexpr int kM  = 256;     // tokens

typedef _Float16 half8 __attribute__((ext_vector_type(8)));  // 8 fp16 (4 VGPRs)
typedef __attribute__((ext_vector_type(4))) float f32x4;     // MFMA accum

// ---------------- helpers ----------------
__device__ __forceinline__ unsigned short f2h(float f) {
  _Float16 h = (_Float16)f;
  return __builtin_bit_cast(unsigned short, h);
}
__device__ __forceinline__ float h2f(unsigned short u) {
  return (float)__builtin_bit_cast(_Float16, u);
}

// ---------------- kernel 0: prep = wprep (64 blocks) + kv (1024 blocks), one launch ----------------
__global__ __launch_bounds__(256) void prep_kernel(
    const float* __restrict__ tokens, const float* __restrict__ tokvW,
    unsigned short* __restrict__ kn_ws, unsigned short* __restrict__ vt_ws,
    const float* __restrict__ tooW, const float* __restrict__ modW0,
    const float* __restrict__ modW1, const float* __restrict__ hvW0,
    const float* __restrict__ qW, const float* __restrict__ bwW0,
    const float* __restrict__ bwW1, const float* __restrict__ toqW,
    unsigned short* __restrict__ tooWt, unsigned short* __restrict__ modW0t,
    unsigned short* __restrict__ modW1t, unsigned short* __restrict__ hvW0t,
    unsigned short* __restrict__ qWt, unsigned short* __restrict__ bw0t,
    unsigned short* __restrict__ bw1t, unsigned short* __restrict__ toqWt)
{
  __shared__ __align__(16) float tok[256];
  int bx = blockIdx.x, tid = threadIdx.x;

  if (bx < kB * kM) {
    // ---- kv part ----
    int b = bx >> 8, j = bx & 255, c = tid;
    tok[c] = tokens[(b * kM + j) * 256 + c];
    __syncthreads();
    float acc = 0.f;
    for (int i4 = 0; i4 < 64; i4++) {
      float4 t4 = *(const float4*)&tok[i4 * 4];
      acc += t4.x * tokvW[(i4*4+0)*256 + c] + t4.y * tokvW[(i4*4+1)*256 + c]
           + t4.z * tokvW[(i4*4+2)*256 + c] + t4.w * tokvW[(i4*4+3)*256 + c];
    }
    unsigned short hv = f2h(acc);
    if (c < 128) {
      int h = c >> 6, dd = c & 63;
      kn_ws[((size_t)(b*2+h)*256 + j) * 64 + dd] = hv;
    } else {
      int c2 = c - 128;
      int h = c2 >> 6, dd = c2 & 63;
      vt_ws[((size_t)(b*2+h)*64 + dd) * 256 + j] = hv;
    }
  } else {
    // ---- wprep part: block t -> (matrix m, K-chunk ch of 8) ----
    int t = bx - kB * kM;          // 0..63
    int m = t >> 3, ch = t & 7;
    const float* Ws[8] = {tooW, modW0, modW1, hvW0, qW, bwW0, bwW1, toqW};
    unsigned short* Wts[8] = {tooWt, modW0t, modW1t, hvW0t, qWt, bw0t, bw1t, toqWt};
    const int Ks[8] = {128, 256, 256, 256, 64, 64, 64, 256};
    const int Ns[8] = {256, 256, 256, 256, 256, 256, 256, 128};
    const float* W = Ws[m];
    unsigned short* Wt = Wts[m];
    int K = Ks[m], N = Ns[m];
    int nkb = K / 8;               // 8, 16 or 32
    int per = nkb >> 3;            // 1, 2 or 4 iters per block
    int kb0 = ch * per;
    if (tid < N) {
      for (int kb = kb0; kb < kb0 + per; kb++) {
        unsigned short sv[8];
#pragma unroll
        for (int i = 0; i < 8; i++)
          sv[i] = f2h(W[(kb * 8 + i) * N + tid]);   // coalesced across tid
        *(uint4*)&Wt[tid * K + kb * 8] = *(const uint4*)sv;
      }
    }
  }
}

// ---------------- kernel 1: fused feat + attn, 32-px blocks (M=32, proven shapes) ----------------
// feat: ff -> 3 GEMMs (xq->LDS, h0/h1->global) -> q GEMM -> qc_s (LDS, reused
// across all 4 batches of the attn loop -- saves the 4MB qc round-trip x4 reads).
// attn: loop b,h: QK^T -> softmax -> PV -> o_hf global.
// C layout (m89-verified): col = lane&15, row = (lane>>4)*4 + reg.
constexpr int kAPitch = 264;   // xq / P_s pitch
constexpr int kQPitch = 136;   // qc pitch

__global__ __launch_bounds__(256, 2) void featattn_kernel(
    const float* __restrict__ coords,
    const float* __restrict__ Bq, const float* __restrict__ Bl0, const float* __restrict__ Bl1,
    const float* __restrict__ qb, const float* __restrict__ bwb0, const float* __restrict__ bwb1,
    const unsigned short* __restrict__ qWt, const unsigned short* __restrict__ bw0t,
    const unsigned short* __restrict__ bw1t, const unsigned short* __restrict__ toqWt,
    const unsigned short* __restrict__ kn_ws, const unsigned short* __restrict__ vt_ws,
    unsigned short* __restrict__ h0_hf, unsigned short* __restrict__ h1_hf,
    unsigned short* __restrict__ o_hf)
{
  // arena: ff [3][32][72] (6912 u16) + xq [32][264] (8448 u16); P_s (8448 u16)
  // aliases offset 0 (ff region) once feat phase is done.
  __shared__ __align__(16) unsigned short arena[15360];
  __shared__ __align__(16) unsigned short qc_s[32 * kQPitch];
  __shared__ float t_s[32];
  __shared__ float coords_s[64];
  __shared__ float red_max[32][4];
  __shared__ float red_sum[32][4];

  unsigned short* ff  = arena;          // [3][32][72]
  unsigned short* xq  = arena + 6912;   // [32][264]
  unsigned short* P_s = arena;          // [32][264], after feat

  int tid = threadIdx.x;
  int px0 = blockIdx.x * 32;
  int w = tid >> 6, ln = tid & 63;
  int c = ln & 15, q = ln >> 4;

  const f32x4 zero4 = {0.f, 0.f, 0.f, 0.f};

  // ===== feat: Fourier features =====
  if (tid < 64) coords_s[tid] = coords[px0 * 2 + tid];
  __syncthreads();

#pragma unroll
  for (int r = 0; r < 24; r++) {
    int v = r * 256 + tid;
    int mat = v >> 11;
    int p = (v >> 6) & 31;
    int f = v & 63;
    int fr = f & 31;
    const float* Bm = (mat == 0) ? Bq : (mat == 1 ? Bl0 : Bl1);
    float x = coords_s[p * 2 + 0];
    float y = coords_s[p * 2 + 1];
    float proj = 6.283185307179586f * (x * Bm[fr*2+0] + y * Bm[fr*2+1]);
    float s, cc;
    __sincosf(proj, &s, &cc);
    ff[(mat * 32 + p) * 72 + f] = f2h((f < 32) ? cc : s);
  }
  if (tid < 32) {
    float x = coords_s[tid * 2 + 0];
    float y = coords_s[tid * 2 + 1];
    int row = min(max((int)(x * 16.0f), 0), 15);
    int col = min(max((int)(y * 16.0f), 0), 15);
    t_s[tid] = (float)(row * 16 + col) * (1.0f / 256.0f);
  }
  __syncthreads();

  // ===== feat: 3 GEMMs M=32, N=256, K=64 =====
  for (int mat = 0; mat < 3; mat++) {
    const unsigned short* Wt = (mat == 0) ? qWt : (mat == 1 ? bw0t : bw1t);
    const float* bias = (mat == 0) ? qb : (mat == 1 ? bwb0 : bwb1);
    f32x4 acc[8];
#pragma unroll
    for (int i = 0; i < 8; i++) acc[i] = zero4;
#pragma unroll
    for (int ks = 0; ks < 2; ks++) {
      int koff = ks * 32 + q * 8;
      half8 bfr[4];
#pragma unroll
      for (int nt = 0; nt < 4; nt++)
        bfr[nt] = *(const half8*)(Wt + (size_t)(w*64 + nt*16 + c) * 64 + koff);
      half8 afr[2];
#pragma unroll
      for (int mt = 0; mt < 2; mt++)
        afr[mt] = *(const half8*)(ff + (mat * 32 + mt*16 + c) * 72 + koff);
#pragma unroll
      for (int mt = 0; mt < 2; mt++)
#pragma unroll
        for (int nt = 0; nt < 4; nt++)
          acc[mt*4+nt] = __builtin_amdgcn_mfma_f32_16x16x32_f16(afr[mt], bfr[nt], acc[mt*4+nt], 0, 0, 0);
    }
    float bv[4];
#pragma unroll
    for (int nt = 0; nt < 4; nt++) bv[nt] = bias[w*64 + nt*16 + c];
#pragma unroll
    for (int mt = 0; mt < 2; mt++)
#pragma unroll
      for (int nt = 0; nt < 4; nt++)
#pragma unroll
        for (int rg = 0; rg < 4; rg++) {
          int row = mt*16 + q*4 + rg, col = w*64 + nt*16 + c;
          unsigned short hv = f2h(fmaxf(acc[mt*4+nt][rg] + bv[nt], 0.f));
          if (mat == 0)      xq[row * kAPitch + col] = hv;
          else if (mat == 1) h0_hf[((size_t)(px0 + row)) * 256 + col] = hv;
          else               h1_hf[((size_t)(px0 + row)) * 256 + col] = hv;
        }
  }
  __syncthreads();   // xq ready

  // ===== feat: q GEMM M=32, N=128, K=256 -> qc_s =====
  {
    f32x4 acc2[4];
#pragma unroll
    for (int i = 0; i < 4; i++) acc2[i] = zero4;
#pragma unroll
    for (int kt = 0; kt < 8; kt++) {
      int koff = kt * 32 + q * 8;
      half8 bfr[2];
#pragma unroll
      for (int nt = 0; nt < 2; nt++)
        bfr[nt] = *(const half8*)(toqWt + (size_t)(w*32 + nt*16 + c) * 256 + koff);
      half8 afr[2];
#pragma unroll
      for (int mt = 0; mt < 2; mt++)
        afr[mt] = *(const half8*)(xq + (mt*16 + c) * kAPitch + koff);
#pragma unroll
      for (int mt = 0; mt < 2; mt++)
#pragma unroll
        for (int nt = 0; nt < 2; nt++)
          acc2[mt*2+nt] = __builtin_amdgcn_mfma_f32_16x16x32_f16(afr[mt], bfr[nt], acc2[mt*2+nt], 0, 0, 0);
    }
#pragma unroll
    for (int mt = 0; mt < 2; mt++)
#pragma unroll
      for (int nt = 0; nt < 2; nt++)
#pragma unroll
        for (int rg = 0; rg < 4; rg++) {
          int row = mt*16 + q*4 + rg, col = w*32 + nt*16 + c;
          qc_s[row * kQPitch + col] = f2h(acc2[mt*2+nt][rg]);
        }
  }
  // (no barrier here: the attn loop's top barrier orders qc/xq hazards)

  // ===== attn: loop over batch & head; qc stays in LDS =====
  for (int b = 0; b < kB; b++) {
    for (int h = 0; h < 2; h++) {
      __syncthreads();   // qc visible; previous P_s reads done

      // QK^T: M=32, N=256 (wave strip of 64), K=64
      f32x4 acc[8];
#pragma unroll
      for (int i = 0; i < 8; i++) acc[i] = zero4;
      const unsigned short* kbase = kn_ws + (size_t)(b*2+h) * 256 * 64;
#pragma unroll
      for (int ks = 0; ks < 2; ks++) {
        int koff = ks * 32 + q * 8;
        half8 a0 = *(const half8*)(qc_s + c * kQPitch + h*64 + koff);
        half8 a1 = *(const half8*)(qc_s + (16 + c) * kQPitch + h*64 + koff);
#pragma unroll
        for (int nt = 0; nt < 4; nt++) {
          half8 bf = *(const half8*)(kbase + (size_t)(w*64 + nt*16 + c) * 64 + koff);
          acc[0*4+nt] = __builtin_amdgcn_mfma_f32_16x16x32_f16(a0, bf, acc[0*4+nt], 0, 0, 0);
          acc[1*4+nt] = __builtin_amdgcn_mfma_f32_16x16x32_f16(a1, bf, acc[1*4+nt], 0, 0, 0);
        }
      }

      // bias + scale, row max
      float lm[2][4];
#pragma unroll
      for (int mt = 0; mt < 2; mt++)
#pragma unroll
        for (int rg = 0; rg < 4; rg++) {
          int row = mt*16 + q*4 + rg;
          float tv = t_s[row];
          float mx = -1e30f;
#pragma unroll
          for (int nt = 0; nt < 4; nt++) {
            int token = w*64 + nt*16 + c;
            float pos = ((float)token + 0.5f) * (1.0f / 256.0f);
            float db = tv - pos;
            float sb = acc[mt*4+nt][rg] * 0.125f - 10.0f * db * db;
            acc[mt*4+nt][rg] = sb;
            mx = fmaxf(mx, sb);
          }
          lm[mt][rg] = mx;
        }
#pragma unroll
      for (int s = 1; s < 16; s <<= 1)
#pragma unroll
        for (int mt = 0; mt < 2; mt++)
#pragma unroll
          for (int rg = 0; rg < 4; rg++)
            lm[mt][rg] = fmaxf(lm[mt][rg], __shfl_xor(lm[mt][rg], s, 64));
      if (c == 0) {
#pragma unroll
        for (int mt = 0; mt < 2; mt++)
#pragma unroll
          for (int rg = 0; rg < 4; rg++)
            red_max[mt*16 + q*4 + rg][w] = lm[mt][rg];
      }
      __syncthreads();

      // exp -> P_s, partial sums
      float ps[2][4];
#pragma unroll
      for (int mt = 0; mt < 2; mt++)
#pragma unroll
        for (int rg = 0; rg < 4; rg++) {
          int row = mt*16 + q*4 + rg;
          float gm = fmaxf(fmaxf(red_max[row][0], red_max[row][1]),
                           fmaxf(red_max[row][2], red_max[row][3]));
          float sum = 0.f;
#pragma unroll
          for (int nt = 0; nt < 4; nt++) {
            float e = __expf(acc[mt*4+nt][rg] - gm);
            sum += e;
            P_s[row * kAPitch + w*64 + nt*16 + c] = f2h(e);
          }
          ps[mt][rg] = sum;
        }
#pragma unroll
      for (int s = 1; s < 16; s <<= 1)
#pragma unroll
        for (int mt = 0; mt < 2; mt++)
#pragma unroll
          for (int rg = 0; rg < 4; rg++)
            ps[mt][rg] += __shfl_xor(ps[mt][rg], s, 64);
      if (c == 0) {
#pragma unroll
        for (int mt = 0; mt < 2; mt++)
#pragma unroll
          for (int rg = 0; rg < 4; rg++)
            red_sum[mt*16 + q*4 + rg][w] = ps[mt][rg];
      }
      __syncthreads();

      // PV: wave w -> dh cols [w*16, w*16+16), K=256
      f32x4 oacc[2] = {zero4, zero4};
      const unsigned short* vbase = vt_ws + (size_t)(b*2+h) * 64 * 256;
#pragma unroll
      for (int kt = 0; kt < 8; kt++) {
        int koff = kt * 32 + q * 8;
        half8 bf = *(const half8*)(vbase + (size_t)(w*16 + c) * 256 + koff);
        half8 a0 = *(const half8*)(P_s + (0*16 + c) * kAPitch + koff);
        half8 a1 = *(const half8*)(P_s + (1*16 + c) * kAPitch + koff);
        oacc[0] = __builtin_amdgcn_mfma_f32_16x16x32_f16(a0, bf, oacc[0], 0, 0, 0);
        oacc[1] = __builtin_amdgcn_mfma_f32_16x16x32_f16(a1, bf, oacc[1], 0, 0, 0);
      }
#pragma unroll
      for (int mt = 0; mt < 2; mt++)
#pragma unroll
        for (int rg = 0; rg < 4; rg++) {
          int row = mt*16 + q*4 + rg;
          float rinv = 1.0f / (red_sum[row][0] + red_sum[row][1] +
                               red_sum[row][2] + red_sum[row][3]);
          o_hf[((size_t)(b * kHW + px0 + row)) * 128 + h*64 + w*16 + c] =
              f2h(oacc[mt][rg] * rinv);
        }
    }
  }
}

// ---------------- kernel 2: MFMA MLP chain, fp16, M=64 rows (16 px x 4 batch) ----------------
// m0 kept in registers (same thread owns same (row,col) across phases);
// h0/h1 direct-to-reg; S into buf0 (free after P1). Barriers 6 -> 5.
constexpr int kPitch = 264;   // fp16 LDS pitch

template <int KD>
__device__ __forceinline__ void gemm4(
    const unsigned short* abuf, const unsigned short* wt,
    f32x4* acc /*[4*4]*/, int c, int q)
{
#pragma unroll
  for (int ks = 0; ks < KD / 32; ks++) {
    int koff = ks * 32 + q * 8;
    half8 bfr[4];
#pragma unroll
    for (int nt = 0; nt < 4; nt++)
      bfr[nt] = *(const half8*)(wt + (nt * 16 + c) * KD + koff);
    half8 afr[4];
#pragma unroll
    for (int mt = 0; mt < 4; mt++)
      afr[mt] = *(const half8*)(abuf + (mt * 16 + c) * kPitch + koff);
#pragma unroll
    for (int mt = 0; mt < 4; mt++)
#pragma unroll
      for (int nt = 0; nt < 4; nt++)
        acc[mt * 4 + nt] = __builtin_amdgcn_mfma_f32_16x16x32_f16(afr[mt], bfr[nt], acc[mt * 4 + nt], 0, 0, 0);
  }
}

__global__ __launch_bounds__(256, 2) void mlp_kernel(
    const unsigned short* __restrict__ o_hf,
    const unsigned short* __restrict__ h0_hf, const unsigned short* __restrict__ h1_hf,
    const unsigned short* __restrict__ tooWt, const float* __restrict__ toob,
    const unsigned short* __restrict__ modW0t, const float* __restrict__ modb0,
    const unsigned short* __restrict__ modW1t, const float* __restrict__ modb1,
    const unsigned short* __restrict__ hvW0t, const float* __restrict__ hvb0,
    const float* __restrict__ outW0, const float* __restrict__ outb0,
    const float* __restrict__ outW1, const float* __restrict__ outb1,
    float* __restrict__ dout)
{
  __shared__ __align__(16) unsigned short buf0[64 * kPitch];  // o, then S
  __shared__ __align__(16) unsigned short buf1[64 * kPitch];  // mod
  __shared__ __align__(16) float scratch[64 * 12];            // out partials

  int tid = threadIdx.x;
  int px0 = blockIdx.x * 16;
  int w = tid >> 6, ln = tid & 63;
  int c = ln & 15, q = ln >> 4;

  // ---- h0/h1 -> registers (each (row,col) needed by exactly this thread) ----
  unsigned short h0r[4][4], h1r[4][4];   // [nt][rg]
#pragma unroll
  for (int nt = 0; nt < 4; nt++) {
    int col = w * 64 + nt * 16 + c;
#pragma unroll
    for (int rg = 0; rg < 4; rg++) {
      int px = q * 4 + rg;
      h0r[nt][rg] = h0_hf[((size_t)(px0 + px)) * 256 + col];
      h1r[nt][rg] = h1_hf[((size_t)(px0 + px)) * 256 + col];
    }
  }

  // ---- stage o (64 rows x 128) ----
#pragma unroll
  for (int i = 0; i < 4; i++) {
    int idx = i * 256 + tid;              // 1024 x uint4 (8 fp16)
    int r = idx >> 4, c8 = (idx & 15) * 8;
    int b = r >> 4, px = r & 15;
    uint4 v = *(const uint4*)(o_hf + ((size_t)(b * kHW + px0 + px)) * 128 + c8);
    *(uint4*)&buf0[r * kPitch + c8] = v;
  }
  __syncthreads();   // B0: o staged

  f32x4 acc[16];
  const f32x4 zero4 = {0.f, 0.f, 0.f, 0.f};

  // ---- P1: mod = o @ tooW + toob -> buf1 ----
#pragma unroll
  for (int i = 0; i < 16; i++) acc[i] = zero4;
  gemm4<128>(buf0, tooWt + (size_t)w * 64 * 128, acc, c, q);
  {
    float bias[4];
#pragma unroll
    for (int nt = 0; nt < 4; nt++) bias[nt] = toob[w * 64 + nt * 16 + c];
#pragma unroll
    for (int mt = 0; mt < 4; mt++)
#pragma unroll
      for (int nt = 0; nt < 4; nt++)
#pragma unroll
        for (int rg = 0; rg < 4; rg++) {
          int row = mt * 16 + q * 4 + rg, col = w * 64 + nt * 16 + c;
          buf1[row * kPitch + col] = f2h(acc[mt * 4 + nt][rg] + bias[nt]);
        }
  }
  __syncthreads();   // B1: mod ready; all o reads done (buf0 free)

  // ---- P2: m0 = relu(h0 + mod @ modW0 + b) -> REGISTERS ----
  _Float16 m0h[4][4][4];   // [mt][nt][rg], 32 VGPR
#pragma unroll
  for (int i = 0; i < 16; i++) acc[i] = zero4;
  gemm4<256>(buf1, modW0t + (size_t)w * 64 * 256, acc, c, q);
  {
    float bias[4];
#pragma unroll
    for (int nt = 0; nt < 4; nt++) bias[nt] = modb0[w * 64 + nt * 16 + c];
#pragma unroll
    for (int mt = 0; mt < 4; mt++)
#pragma unroll
      for (int nt = 0; nt < 4; nt++)
#pragma unroll
        for (int rg = 0; rg < 4; rg++)
          m0h[mt][nt][rg] =
              (_Float16)fmaxf(acc[mt * 4 + nt][rg] + bias[nt] + h2f(h0r[nt][rg]), 0.f);
  }

  // ---- P3: m1 = relu(h1 + mod @ modW1 + b); S = m0 + m1 -> buf0 ----
#pragma unroll
  for (int i = 0; i < 16; i++) acc[i] = zero4;
  gemm4<256>(buf1, modW1t + (size_t)w * 64 * 256, acc, c, q);
  {
    float bias[4];
#pragma unroll
    for (int nt = 0; nt < 4; nt++) bias[nt] = modb1[w * 64 + nt * 16 + c];
#pragma unroll
    for (int mt = 0; mt < 4; mt++)
#pragma unroll
      for (int nt = 0; nt < 4; nt++)
#pragma unroll
        for (int rg = 0; rg < 4; rg++) {
          int row = mt * 16 + q * 4 + rg, col = w * 64 + nt * 16 + c;
          float m0v = (float)m0h[mt][nt][rg];
          float v = m0v + fmaxf(acc[mt * 4 + nt][rg] + bias[nt] + h2f(h1r[nt][rg]), 0.f);
          buf0[row * kPitch + col] = f2h(v);
        }
  }
  __syncthreads();   // B2: S ready in buf0 (mod reads complete for this wave's writes? -- yes: buf0 write, buf1 read, disjoint)

  // ---- P4: hv1 = relu(S @ hvW0 + b); fused out epilogue (m0 from regs) ----
#pragma unroll
  for (int i = 0; i < 16; i++) acc[i] = zero4;
  gemm4<256>(buf0, hvW0t + (size_t)w * 64 * 256, acc, c, q);
  {
    float bias[4], w0v[4][3], w1v[4][3];
#pragma unroll
    for (int nt = 0; nt < 4; nt++) {
      int col = w * 64 + nt * 16 + c;
      bias[nt] = hvb0[col];
#pragma unroll
      for (int k = 0; k < 3; k++) {
        w0v[nt][k] = outW0[col * 3 + k];
        w1v[nt][k] = outW1[col * 3 + k];
      }
    }
#pragma unroll
    for (int mt = 0; mt < 4; mt++) {
      float pk[4][3];
#pragma unroll
      for (int rg = 0; rg < 4; rg++)
#pragma unroll
        for (int k = 0; k < 3; k++) pk[rg][k] = 0.f;
#pragma unroll
      for (int nt = 0; nt < 4; nt++) {
#pragma unroll
        for (int rg = 0; rg < 4; rg++) {
          float hv1 = fmaxf(acc[mt * 4 + nt][rg] + bias[nt], 0.f);
          float m0v = (float)m0h[mt][nt][rg];
#pragma unroll
          for (int k = 0; k < 3; k++)
            pk[rg][k] += m0v * w0v[nt][k] + hv1 * w1v[nt][k];
        }
      }
#pragma unroll
      for (int s = 1; s < 16; s <<= 1)
#pragma unroll
        for (int rg = 0; rg < 4; rg++)
#pragma unroll
          for (int k = 0; k < 3; k++)
            pk[rg][k] += __shfl_xor(pk[rg][k], s, 64);
      if (c == 0) {
#pragma unroll
        for (int rg = 0; rg < 4; rg++) {
          int row = mt * 16 + q * 4 + rg;
#pragma unroll
          for (int k = 0; k < 3; k++)
            scratch[row * 12 + k * 4 + w] = pk[rg][k];
        }
      }
    }
  }
  __syncthreads();   // B3

  if (tid < 192) {
    int row = tid / 3, k = tid % 3;
    int b = row >> 4, px = px0 + (row & 15);
    float s = outb0[k] + outb1[k];
#pragma unroll
    for (int ww = 0; ww < 4; ww++) s += scratch[row * 12 + k * 4 + ww];
    dout[((size_t)b * kHW + px) * 3 + k] = s;
  }
}

// ---------------- launch ----------------
extern "C" void kernel_launch(void* const* d_in, const int* in_sizes, int n_in,
                              void* d_out, int out_size, void* d_ws, size_t ws_size,
                              hipStream_t stream) {
  const float* coords = (const float*)d_in[0];
  const float* tokens = (const float*)d_in[1];
  const float* Bq     = (const float*)d_in[2];
  const float* Bl0    = (const float*)d_in[3];
  const float* Bl1    = (const float*)d_in[4];
  const float* qW     = (const float*)d_in[5];
  const float* qb     = (const float*)d_in[6];
  const float* toqW   = (const float*)d_in[7];
  const float* tokvW  = (const float*)d_in[8];
  const float* tooW   = (const float*)d_in[9];
  const float* toob   = (const float*)d_in[10];
  const float* bwW0   = (const float*)d_in[11];
  const float* bwb0   = (const float*)d_in[12];
  const float* bwW1   = (const float*)d_in[13];
  const float* bwb1   = (const float*)d_in[14];
  const float* modW0  = (const float*)d_in[15];
  const float* modb0  = (const float*)d_in[16];
  const float* modW1  = (const float*)d_in[17];
  const float* modb1  = (const float*)d_in[18];
  const float* hvW0   = (const float*)d_in[19];
  const float* hvb0   = (const float*)d_in[20];
  const float* outW0  = (const float*)d_in[21];
  const float* outb0  = (const float*)d_in[22];
  const float* outW1  = (const float*)d_in[23];
  const float* outb1  = (const float*)d_in[24];

  char* ws = (char*)d_ws;
  unsigned short* h0_hf  = (unsigned short*)(ws + 0);         //    8 MB
  unsigned short* h1_hf  = (unsigned short*)(ws + 8388608);   //    8 MB
  unsigned short* o_hf   = (unsigned short*)(ws + 16777216);  //   16 MB
  unsigned short* kn_ws  = (unsigned short*)(ws + 33554432);  //  256 KB
  unsigned short* vt_ws  = (unsigned short*)(ws + 33816576);  //  256 KB
  unsigned short* tooWt  = (unsigned short*)(ws + 34078720);  //   64 KB
  unsigned short* modW0t = (unsigned short*)(ws + 34144256);  //  128 KB
  unsigned short* modW1t = (unsigned short*)(ws + 34275328);  //  128 KB
  unsigned short* hvW0t  = (unsigned short*)(ws + 34406400);  //  128 KB
  unsigned short* qWt    = (unsigned short*)(ws + 34537472);  //   32 KB
  unsigned short* bw0t   = (unsigned short*)(ws + 34570240);  //   32 KB
  unsigned short* bw1t   = (unsigned short*)(ws + 34603008);  //   32 KB
  unsigned short* toqWt  = (unsigned short*)(ws + 34635776);  //   64 KB

  prep_kernel<<<dim3(kB * kM + 64), 256, 0, stream>>>(
      tokens, tokvW, kn_ws, vt_ws,
      tooW, modW0, modW1, hvW0, qW, bwW0, bwW1, toqW,
      tooWt, modW0t, modW1t, hvW0t, qWt, bw0t, bw1t, toqWt);
  featattn_kernel<<<dim3(kHW / 32), 256, 0, stream>>>(
      coords, Bq, Bl0, Bl1, qb, bwb0, bwb1,
      qWt, bw0t, bw1t, toqWt,
      kn_ws, vt_ws,
      h0_hf, h1_hf, o_hf);
  mlp_kernel<<<dim3(kHW / 16), 256, 0, stream>>>(
      o_hf, h0_hf, h1_hf, tooWt, toob, modW0t, modb0, modW1t, modb1,
      hvW0t, hvb0, outW0, outb0, outW1, outb1, (float*)d_out);
}